// Round 8
// baseline (155.537 us; speedup 1.0000x reference)
//
#include <hip/hip_runtime.h>
#include <math.h>

// B=2048, L=64, D=512. Only out[:,0] needed.
// q = (x0+pe0)@We_q^T + be_q (bf16). All score terms from q:
//   QKE[b,d] = sum_n q[b,n]*We_k[n,d]  (B = WekT = We_k^T, +rows be_k/br_k -> qbk/qbr)
//   SD[b,j]  = sum_n q[b,n]*GP[j,n],  GP = Paug@Wkb^T (weights-only)
//   RW[b,n]  = sum_d rel[b,d]*Wr_k[n,d];  crr = q.RW + qbr
// attn (one block per b): x[b] staged fp32 HBM->LDS via global_load_lds
//   (8-row batches, double-buffered, counted vmcnt gates); convert+dot pass
//   writes bf16 xs + scores; softmax; vectorized wave-split weighted sum.
// out = A@Bt^T + spe*be_v + spr*br_v;  Bt = [We_v|Wr_v | U^T | 0].

using s16x8 = __attribute__((ext_vector_type(8))) short;
using f32x4 = __attribute__((ext_vector_type(4))) float;

#define S12 1216

static __device__ __forceinline__ float bf2f(unsigned short s) {
  union { unsigned u; float f; } c; c.u = ((unsigned)s) << 16; return c.f;
}
static __device__ __forceinline__ unsigned short f2bf(float f) {
  union { float f; unsigned u; } c; c.f = f;
  unsigned u = c.u;
  unsigned r = (u + 0x7fffu + ((u >> 16) & 1u)) >> 16;
  return (unsigned short)r;
}

template <int K>
__device__ __forceinline__ void mfma64(
    const unsigned short* __restrict__ Ab, int lda,
    const unsigned short* __restrict__ Bb, int ldb,
    int wm, int wn, int lr, int koff, f32x4 acc[2][2]) {
#pragma unroll
  for (int k0 = 0; k0 < K; k0 += 32) {
    s16x8 a[2], b[2];
#pragma unroll
    for (int im = 0; im < 2; ++im)
      a[im] = *(const s16x8*)(Ab + (size_t)(wm + im * 16 + lr) * lda + k0 + koff);
#pragma unroll
    for (int in = 0; in < 2; ++in)
      b[in] = *(const s16x8*)(Bb + (size_t)(wn + in * 16 + lr) * ldb + k0 + koff);
#pragma unroll
    for (int im = 0; im < 2; ++im)
#pragma unroll
      for (int in = 0; in < 2; ++in)
        acc[im][in] = __builtin_amdgcn_mfma_f32_16x16x32_bf16(a[im], b[in], acc[im][in], 0, 0, 0);
  }
}

// ---------------- prep ----------------
__global__ __launch_bounds__(256) void prep_kernel(
    const float* __restrict__ x, const float* __restrict__ rel,
    const float* __restrict__ pos_e, const float* __restrict__ pos_r,
    const float* __restrict__ maskv, const float* __restrict__ We_q,
    const float* __restrict__ We_k, const float* __restrict__ Wr_k,
    const float* __restrict__ We_v, const float* __restrict__ Wr_v,
    const float* __restrict__ be_k, const float* __restrict__ br_k,
    unsigned short* __restrict__ Xp, unsigned short* __restrict__ relb,
    unsigned short* __restrict__ Weqb, unsigned short* __restrict__ Wkb,
    unsigned short* __restrict__ WekT, unsigned short* __restrict__ Bt,
    unsigned short* __restrict__ Paug) {
  const int blk = blockIdx.x, tid = threadIdx.x;
  __shared__ float ts[64][65];
  if (blk < 2048) {
    float2 v = *(const float2*)(x + (size_t)blk * 32768 + tid * 2);
    float2 pe = *(const float2*)(pos_e + tid * 2);
    ushort2 o;
    o.x = f2bf(v.x + pe.x);
    o.y = f2bf(v.y + pe.y);
    *(ushort2*)(Xp + (size_t)blk * 512 + tid * 2) = o;
    float2 rv = *(const float2*)(rel + (size_t)blk * 512 + tid * 2);
    ushort2 ro;
    ro.x = f2bf(rv.x);
    ro.y = f2bf(rv.y);
    *(ushort2*)(relb + (size_t)blk * 512 + tid * 2) = ro;
  } else if (blk < 2176) {
    const int e = ((blk - 2048) * 256 + tid) * 8;
    float4 a0 = *(const float4*)(We_q + e);
    float4 a1 = *(const float4*)(We_q + e + 4);
    ushort4 o0, o1;
    o0.x = f2bf(a0.x); o0.y = f2bf(a0.y); o0.z = f2bf(a0.z); o0.w = f2bf(a0.w);
    o1.x = f2bf(a1.x); o1.y = f2bf(a1.y); o1.z = f2bf(a1.z); o1.w = f2bf(a1.w);
    *(ushort4*)(Weqb + e) = o0;
    *(ushort4*)(Weqb + e + 4) = o1;
  } else if (blk < 2432) {
    const int e = ((blk - 2176) * 256 + tid) * 8;
    const int n = e >> 10, k = e & 1023;
    const float* src = (k < 512) ? (We_k + (size_t)n * 512 + k)
                                 : (Wr_k + (size_t)n * 512 + k - 512);
    float4 v0 = *(const float4*)src;
    float4 v1 = *(const float4*)(src + 4);
    ushort4 o0, o1;
    o0.x = f2bf(v0.x); o0.y = f2bf(v0.y); o0.z = f2bf(v0.z); o0.w = f2bf(v0.w);
    o1.x = f2bf(v1.x); o1.y = f2bf(v1.y); o1.z = f2bf(v1.z); o1.w = f2bf(v1.w);
    *(ushort4*)(Wkb + e) = o0;
    *(ushort4*)(Wkb + e + 4) = o1;
  } else if (blk < 2496) {
    const int tr = blk - 2432;
    const int td0 = (tr >> 3) * 64, tn0 = (tr & 7) * 64;
    const int r = tid >> 2, cq = (tid & 3) * 16;
#pragma unroll
    for (int i = 0; i < 16; i += 4) {
      float4 v = *(const float4*)(We_k + (size_t)(tn0 + r) * 512 + td0 + cq + i);
      ts[r][cq + i + 0] = v.x;
      ts[r][cq + i + 1] = v.y;
      ts[r][cq + i + 2] = v.z;
      ts[r][cq + i + 3] = v.w;
    }
    __syncthreads();
#pragma unroll
    for (int i = 0; i < 16; i += 4) {
      ushort4 o;
      o.x = f2bf(ts[cq + i + 0][r]);
      o.y = f2bf(ts[cq + i + 1][r]);
      o.z = f2bf(ts[cq + i + 2][r]);
      o.w = f2bf(ts[cq + i + 3][r]);
      *(ushort4*)(WekT + (size_t)(td0 + r) * 512 + tn0 + cq + i) = o;
    }
  } else if (blk == 2496) {
    WekT[(size_t)512 * 512 + tid] = f2bf(be_k[tid]);
    WekT[(size_t)512 * 512 + 256 + tid] = f2bf(be_k[256 + tid]);
    WekT[(size_t)513 * 512 + tid] = f2bf(br_k[tid]);
    WekT[(size_t)513 * 512 + 256 + tid] = f2bf(br_k[256 + tid]);
  } else if (blk < 2513) {
    const int e = ((blk - 2497) * 256 + tid) * 8;
    if (e < 62 * 512) {
      ushort4 z = {0, 0, 0, 0};
      *(ushort4*)(WekT + (size_t)514 * 512 + e) = z;
      *(ushort4*)(WekT + (size_t)514 * 512 + e + 4) = z;
    }
  } else if (blk < 3025) {
    const int base = ((blk - 2513) * 256 + tid) * 4;
    const int n = base >> 10, k = base & 1023;
    const float* src = (k < 512) ? (We_v + (size_t)n * 512 + k)
                                 : (Wr_v + (size_t)n * 512 + k - 512);
    float4 v = *(const float4*)src;
    ushort4 o;
    o.x = f2bf(v.x); o.y = f2bf(v.y); o.z = f2bf(v.z); o.w = f2bf(v.w);
    *(ushort4*)(Bt + (size_t)n * S12 + k) = o;
  } else if (blk < 3041) {
    const int t = (blk - 3025) * 256 + tid;
    const int n = t >> 3, c0 = 1152 + (t & 7) * 8;
    ushort4 z = {0, 0, 0, 0};
    *(ushort4*)(Bt + (size_t)n * S12 + c0) = z;
    *(ushort4*)(Bt + (size_t)n * S12 + c0 + 4) = z;
  } else {
    const int idx = (blk - 3041) * 256 + tid;
    const int e = idx * 8;
    const int j = e >> 10, c = e & 1023;
    ushort4 o0 = {0, 0, 0, 0}, o1 = {0, 0, 0, 0};
    if (j < 65 && c < 512) {
      float4 v0 = *(const float4*)(pos_e + (size_t)j * 512 + c);
      float4 v1 = *(const float4*)(pos_e + (size_t)j * 512 + c + 4);
      if (j == 64) {
        float4 m0 = *(const float4*)(maskv + c);
        float4 m1 = *(const float4*)(maskv + c + 4);
        v0.x += m0.x; v0.y += m0.y; v0.z += m0.z; v0.w += m0.w;
        v1.x += m1.x; v1.y += m1.y; v1.z += m1.z; v1.w += m1.w;
      }
      o0.x = f2bf(v0.x); o0.y = f2bf(v0.y); o0.z = f2bf(v0.z); o0.w = f2bf(v0.w);
      o1.x = f2bf(v1.x); o1.y = f2bf(v1.y); o1.z = f2bf(v1.z); o1.w = f2bf(v1.w);
    } else if (j >= 65 && j < 129 && c >= 512) {
      float4 v0 = *(const float4*)(pos_r + (size_t)(j - 65) * 512 + c - 512);
      float4 v1 = *(const float4*)(pos_r + (size_t)(j - 65) * 512 + c - 512 + 4);
      o0.x = f2bf(v0.x); o0.y = f2bf(v0.y); o0.z = f2bf(v0.z); o0.w = f2bf(v0.w);
      o1.x = f2bf(v1.x); o1.y = f2bf(v1.y); o1.z = f2bf(v1.z); o1.w = f2bf(v1.w);
    }
    *(ushort4*)(Paug + e) = o0;
    *(ushort4*)(Paug + e + 4) = o1;
  }
}

// ---- g1: q | RW | GP | U ----
__global__ __launch_bounds__(256) void g1_kernel(
    const unsigned short* __restrict__ Xp, const unsigned short* __restrict__ Weqb,
    const float* __restrict__ be_q, const unsigned short* __restrict__ relb,
    const unsigned short* __restrict__ Wkb, const unsigned short* __restrict__ Paug,
    unsigned short* __restrict__ Bt, unsigned short* __restrict__ qb,
    float* __restrict__ RW, unsigned short* __restrict__ GP) {
  int blk = blockIdx.x;
  const int tid = threadIdx.x;
  const int wid = tid >> 6, lane = tid & 63;
  const int wm = (wid >> 1) * 32, wn = (wid & 1) * 32;
  const int lr = lane & 15, koff = (lane >> 4) * 8;
  const int r0 = (lane >> 4) * 4;
  f32x4 acc[2][2] = {};
  if (blk < 256) {
    const int bm = (blk >> 3) * 64, bn = (blk & 7) * 64;
    mfma64<512>(Xp + (size_t)bm * 512, 512, Weqb + (size_t)bn * 512, 512,
                wm, wn, lr, koff, acc);
#pragma unroll
    for (int im = 0; im < 2; ++im)
#pragma unroll
      for (int in = 0; in < 2; ++in)
#pragma unroll
        for (int i = 0; i < 4; ++i) {
          const int row = bm + wm + im * 16 + r0 + i;
          const int col = bn + wn + in * 16 + lr;
          qb[(size_t)row * 512 + col] = f2bf(acc[im][in][i] + be_q[col]);
        }
  } else if (blk < 512) {
    blk -= 256;
    const int bm = (blk >> 3) * 64, bn = (blk & 7) * 64;
    mfma64<512>(relb + (size_t)bm * 512, 512, Wkb + (size_t)bn * 1024 + 512, 1024,
                wm, wn, lr, koff, acc);
#pragma unroll
    for (int im = 0; im < 2; ++im)
#pragma unroll
      for (int in = 0; in < 2; ++in)
#pragma unroll
        for (int i = 0; i < 4; ++i) {
          const int row = bm + wm + im * 16 + r0 + i;
          const int col = bn + wn + in * 16 + lr;
          RW[(size_t)row * 512 + col] = acc[im][in][i];
        }
  } else if (blk < 536) {
    blk -= 512;
    const int bm = (blk >> 3) * 64, bn = (blk & 7) * 64;
    mfma64<1024>(Paug + (size_t)bm * 1024, 1024, Wkb + (size_t)bn * 1024, 1024,
                 wm, wn, lr, koff, acc);
#pragma unroll
    for (int im = 0; im < 2; ++im)
#pragma unroll
      for (int in = 0; in < 2; ++in)
#pragma unroll
        for (int i = 0; i < 4; ++i) {
          const int row = bm + wm + im * 16 + r0 + i;
          const int col = bn + wn + in * 16 + lr;
          GP[(size_t)row * 512 + col] = f2bf(acc[im][in][i]);
        }
  } else {
    blk -= 536;
    const int bm = (blk >> 3) * 64, bn = (blk & 7) * 64;
    mfma64<1024>(Paug + (size_t)bm * 1024, 1024, Bt + (size_t)bn * S12, S12,
                 wm, wn, lr, koff, acc);
#pragma unroll
    for (int im = 0; im < 2; ++im)
#pragma unroll
      for (int in = 0; in < 2; ++in)
#pragma unroll
        for (int i = 0; i < 4; ++i) {
          const int row = bm + wm + im * 16 + r0 + i;
          const int col = bn + wn + in * 16 + lr;
          if (row < 129)
            Bt[(size_t)col * S12 + 1024 + row] = f2bf(acc[im][in][i]);
        }
  }
}

// ---- g2: QKE (fp32, incl qbk/qbr) | SD (fp32) ----
__global__ __launch_bounds__(256) void g2_kernel(
    const unsigned short* __restrict__ qb, const unsigned short* __restrict__ WekT,
    const unsigned short* __restrict__ GP, float* __restrict__ qke,
    float* __restrict__ sd) {
  int blk = blockIdx.x;
  const int tid = threadIdx.x;
  const int wid = tid >> 6, lane = tid & 63;
  const int wm = (wid >> 1) * 32, wn = (wid & 1) * 32;
  const int lr = lane & 15, koff = (lane >> 4) * 8;
  const int r0 = (lane >> 4) * 4;
  f32x4 acc[2][2] = {};
  if (blk < 288) {
    const int bm = (blk / 9) * 64, bn = (blk % 9) * 64;
    mfma64<512>(qb + (size_t)bm * 512, 512, WekT + (size_t)bn * 512, 512,
                wm, wn, lr, koff, acc);
#pragma unroll
    for (int im = 0; im < 2; ++im)
#pragma unroll
      for (int in = 0; in < 2; ++in)
#pragma unroll
        for (int i = 0; i < 4; ++i) {
          const int row = bm + wm + im * 16 + r0 + i;
          const int col = bn + wn + in * 16 + lr;
          qke[(size_t)row * 576 + col] = acc[im][in][i];
        }
  } else {
    blk -= 288;
    const int bm = (blk / 3) * 64, bn = (blk % 3) * 64;
    mfma64<512>(qb + (size_t)bm * 512, 512, GP + (size_t)bn * 512, 512,
                wm, wn, lr, koff, acc);
#pragma unroll
    for (int im = 0; im < 2; ++im)
#pragma unroll
      for (int in = 0; in < 2; ++in)
#pragma unroll
        for (int i = 0; i < 4; ++i) {
          const int row = bm + wm + im * 16 + r0 + i;
          const int col = bn + wn + in * 16 + lr;
          sd[(size_t)row * 192 + col] = acc[im][in][i];
        }
  }
}

// ------ attn: gload_lds deep-pipelined staging + convert/dot + softmax ------
__global__ __launch_bounds__(512, 1) void attn_kernel(
    const float* __restrict__ x, const float* __restrict__ rel,
    const float* __restrict__ qke, const float* __restrict__ sd,
    const unsigned short* __restrict__ qb, const float* __restrict__ RW,
    unsigned short* __restrict__ A, float* __restrict__ spe_g,
    float* __restrict__ spr_g) {
  __shared__ float stage[2][8 * 512];       // 2 x 16 KB fp32 staging
  __shared__ unsigned short xs[64 * 512];   // 64 KB bf16
  __shared__ unsigned short part[8 * 512];  // 8 KB bf16 partials
  __shared__ float sdl[192];
  __shared__ float sc[64];
  __shared__ float pvv[129];
  __shared__ float scx[8];
  const int b = blockIdx.x;
  const int tid = threadIdx.x;
  const int wid = tid >> 6, lane = tid & 63;
  const int j0 = wid * 8;
  const float scale = 0.04419417382415922f;  // 1/sqrt(512)
  const float* xb = x + (size_t)b * 32768;

  // ---- prologue global loads (all consumed before staging loop) ----
  if (tid < 192) sdl[tid] = sd[(size_t)b * 192 + tid];
  if (tid == 200) scx[1] = qke[(size_t)b * 576 + 512];  // qbk
  float qe[8];
  {
    float4 a0 = *(const float4*)(qke + (size_t)b * 576 + lane * 8);
    float4 a1 = *(const float4*)(qke + (size_t)b * 576 + lane * 8 + 4);
    qe[0] = a0.x; qe[1] = a0.y; qe[2] = a0.z; qe[3] = a0.w;
    qe[4] = a1.x; qe[5] = a1.y; qe[6] = a1.z; qe[7] = a1.w;
  }
  if (wid == 7) {  // crr = q.RW + qbr
    s16x8 qv = *(const s16x8*)(qb + (size_t)b * 512 + lane * 8);
    float4 r0 = *(const float4*)(RW + (size_t)b * 512 + lane * 8);
    float4 r1 = *(const float4*)(RW + (size_t)b * 512 + lane * 8 + 4);
    float s = bf2f(qv[0]) * r0.x + bf2f(qv[1]) * r0.y + bf2f(qv[2]) * r0.z +
              bf2f(qv[3]) * r0.w + bf2f(qv[4]) * r1.x + bf2f(qv[5]) * r1.y +
              bf2f(qv[6]) * r1.z + bf2f(qv[7]) * r1.w;
#pragma unroll
    for (int off = 32; off > 0; off >>= 1) s += __shfl_xor(s, off);
    if (lane == 0) scx[0] = s + qke[(size_t)b * 576 + 513];
  }

  // ---- staging pipeline: 8 batches x 8 rows, double-buffered ----
  // batch i: global bytes [i*16KB, (i+1)*16KB); wave w covers its 2KB slice
  // (2 x global_load_lds dwordx4: lds dest = uniform base + lane*16)
  float a8[8];
#pragma unroll
  for (int r = 0; r < 8; ++r) a8[r] = 0.f;

  __builtin_amdgcn_sched_barrier(0);
  asm volatile("s_waitcnt vmcnt(0)" ::: "memory");
  __builtin_amdgcn_sched_barrier(0);

#define ISSUE_BATCH(i)                                                        \
  {                                                                           \
    const float* gsrc = xb + (i) * 4096 + wid * 512;                          \
    float* ldst = &stage[(i) & 1][wid * 512];                                 \
    __builtin_amdgcn_global_load_lds(                                         \
        (const __attribute__((address_space(1))) void*)(gsrc + lane * 4),     \
        (__attribute__((address_space(3))) void*)(ldst), 16, 0, 0);           \
    __builtin_amdgcn_global_load_lds(                                         \
        (const __attribute__((address_space(1))) void*)(gsrc + 256 + lane * 4),\
        (__attribute__((address_space(3))) void*)(ldst + 256), 16, 0, 0);     \
  }

  ISSUE_BATCH(0);
#pragma unroll
  for (int i = 0; i < 8; ++i) {
    if (i < 7) ISSUE_BATCH(i + 1);
    if (i < 7)
      asm volatile("s_waitcnt vmcnt(2)" ::: "memory");
    else
      asm volatile("s_waitcnt vmcnt(0)" ::: "memory");
    __builtin_amdgcn_sched_barrier(0);
    __builtin_amdgcn_s_barrier();
    // compute batch i: wave w handles row w of the batch (global row i*8+w)
    {
      const float* srow = &stage[i & 1][wid * 512];
      float4 v0 = *(const float4*)(srow + lane * 8);
      float4 v1 = *(const float4*)(srow + lane * 8 + 4);
      const int j = i * 8 + wid;
      s16x8 u;
      u[0] = (short)f2bf(v0.x); u[1] = (short)f2bf(v0.y);
      u[2] = (short)f2bf(v0.z); u[3] = (short)f2bf(v0.w);
      u[4] = (short)f2bf(v1.x); u[5] = (short)f2bf(v1.y);
      u[6] = (short)f2bf(v1.z); u[7] = (short)f2bf(v1.w);
      *(s16x8*)(xs + (size_t)j * 512 + lane * 8) = u;
      a8[i] = qe[0] * v0.x + qe[1] * v0.y + qe[2] * v0.z + qe[3] * v0.w +
              qe[4] * v1.x + qe[5] * v1.y + qe[6] * v1.z + qe[7] * v1.w;
    }
    __builtin_amdgcn_s_barrier();
    __builtin_amdgcn_sched_barrier(0);
  }
#undef ISSUE_BATCH

  // reduce dots: a8[i] = score of row i*8+wid
#pragma unroll
  for (int off = 32; off > 0; off >>= 1) {
#pragma unroll
    for (int r = 0; r < 8; ++r) a8[r] += __shfl_xor(a8[r], off);
  }
  if (lane == 0) {
#pragma unroll
    for (int r = 0; r < 8; ++r) sc[r * 8 + wid] = a8[r];
  }
  __syncthreads();

  // softmax over 129 (wave 0)
  if (wid == 0) {
    const float crr = scx[0];
    const float qbk = scx[1];
    float v1 = (sc[lane] + sdl[lane] + qbk) * scale;
    float v2 = (lane == 0) ? (sdl[64] + qbk) * scale : (sdl[64 + lane] + crr) * scale;
    float v3 = (lane == 0) ? (sdl[128] + crr) * scale : -1e30f;
    float m = fmaxf(fmaxf(v1, v2), v3);
#pragma unroll
    for (int off = 32; off > 0; off >>= 1) m = fmaxf(m, __shfl_xor(m, off));
    float e1 = __expf(v1 - m);
    float e2 = __expf(v2 - m);
    float e3 = (lane == 0) ? __expf(v3 - m) : 0.f;
    float se = e1 + ((lane == 0) ? e2 : 0.f);
    float sr = ((lane == 0) ? 0.f : e2) + e3;
#pragma unroll
    for (int off = 32; off > 0; off >>= 1) {
      se += __shfl_xor(se, off);
      sr += __shfl_xor(sr, off);
    }
    float inv = 1.f / (se + sr);
    float p1 = e1 * inv, p2 = e2 * inv;
    pvv[lane] = p1;
    pvv[64 + lane] = p2;
    unsigned short* Ab = A + (size_t)b * S12;
    Ab[1024 + lane] = f2bf(p1);
    Ab[1088 + lane] = f2bf(p2);
    if (lane == 0) {
      float p3 = e3 * inv;
      pvv[128] = p3;
      Ab[1152] = f2bf(p3);
      scx[4] = sr * inv;
      spe_g[b] = se * inv;
      spr_g[b] = sr * inv;
    } else {
      Ab[1152 + lane] = 0;
    }
  }
  __syncthreads();

  // epilogue: wave w sums rows j0..j0+7 (vector LDS reads) -> bf16 partials
  {
    float acc8[8] = {};
#pragma unroll
    for (int r = 0; r < 8; ++r) {
      const float p = pvv[j0 + r];
      s16x8 xv = *(const s16x8*)(xs + (size_t)(j0 + r) * 512 + lane * 8);
      acc8[0] += p * bf2f(xv[0]); acc8[1] += p * bf2f(xv[1]);
      acc8[2] += p * bf2f(xv[2]); acc8[3] += p * bf2f(xv[3]);
      acc8[4] += p * bf2f(xv[4]); acc8[5] += p * bf2f(xv[5]);
      acc8[6] += p * bf2f(xv[6]); acc8[7] += p * bf2f(xv[7]);
    }
    s16x8 o;
#pragma unroll
    for (int i = 0; i < 8; ++i) o[i] = (short)f2bf(acc8[i]);
    *(s16x8*)(part + wid * 512 + lane * 8) = o;
  }
  __syncthreads();
  {
    float s = 0.f;
#pragma unroll
    for (int w = 0; w < 8; ++w) s += bf2f(part[w * 512 + tid]);
    unsigned short* Ab = A + (size_t)b * S12;
    Ab[tid] = f2bf(s);
    Ab[512 + tid] = f2bf(scx[4] * rel[(size_t)b * 512 + tid]);
  }
}

// ---- out = A @ Bt^T + spe*be_v + spr*br_v ----
__global__ __launch_bounds__(256) void out_mfma_kernel(
    const unsigned short* __restrict__ A, const unsigned short* __restrict__ Bt,
    const float* __restrict__ be_v, const float* __restrict__ br_v,
    const float* __restrict__ spe, const float* __restrict__ spr,
    float* __restrict__ outp) {
  const int bn = blockIdx.x * 64;
  const int bm = blockIdx.y * 64;
  const int tid = threadIdx.x;
  const int wid = tid >> 6, lane = tid & 63;
  const int wm = (wid >> 1) * 32, wn = (wid & 1) * 32;
  const int lr = lane & 15, koff = (lane >> 4) * 8;
  f32x4 acc[2][2] = {};
  mfma64<S12>(A + (size_t)bm * S12, S12, Bt + (size_t)bn * S12, S12,
              wm, wn, lr, koff, acc);
  const int r0 = (lane >> 4) * 4;
#pragma unroll
  for (int im = 0; im < 2; ++im)
#pragma unroll
    for (int i = 0; i < 4; ++i) {
      const int row = bm + wm + im * 16 + r0 + i;
      const float se = spe[row], sr = spr[row];
#pragma unroll
      for (int in = 0; in < 2; ++in) {
        const int col = bn + wn + in * 16 + lr;
        outp[(size_t)row * 512 + col] = acc[im][in][i] + se * be_v[col] + sr * br_v[col];
      }
    }
}

extern "C" void kernel_launch(void* const* d_in, const int* in_sizes, int n_in,
                              void* d_out, int out_size, void* d_ws, size_t ws_size,
                              hipStream_t stream) {
  const float* x     = (const float*)d_in[0];
  const float* rel   = (const float*)d_in[1];
  const float* maskv = (const float*)d_in[2];
  const float* pos_e = (const float*)d_in[3];
  const float* pos_r = (const float*)d_in[4];
  const float* We_q  = (const float*)d_in[5];
  const float* be_q  = (const float*)d_in[6];
  const float* We_k  = (const float*)d_in[7];
  const float* be_k  = (const float*)d_in[8];
  const float* We_v  = (const float*)d_in[9];
  const float* be_v  = (const float*)d_in[10];
  const float* Wr_k  = (const float*)d_in[13];
  const float* br_k  = (const float*)d_in[14];
  const float* Wr_v  = (const float*)d_in[15];
  const float* br_v  = (const float*)d_in[16];

  char* p = (char*)d_ws;
  float* qke = (float*)p;                     p += (size_t)2048 * 576 * 4;
  float* sd  = (float*)p;                     p += (size_t)2048 * 192 * 4;
  float* RW  = (float*)p;                     p += (size_t)2048 * 512 * 4;
  float* spe = (float*)p;                     p += 2048 * 4;
  float* spr = (float*)p;                     p += 2048 * 4;
  unsigned short* qb   = (unsigned short*)p;  p += (size_t)2048 * 512 * 2;
  unsigned short* A    = (unsigned short*)p;  p += (size_t)2048 * S12 * 2;
  unsigned short* Bt   = (unsigned short*)p;  p += (size_t)512 * S12 * 2;
  unsigned short* WekT = (unsigned short*)p;  p += (size_t)576 * 512 * 2;
  unsigned short* Weqb = (unsigned short*)p;  p += (size_t)512 * 512 * 2;
  unsigned short* Wkb  = (unsigned short*)p;  p += (size_t)512 * 1024 * 2;
  unsigned short* GP   = (unsigned short*)p;  p += (size_t)192 * 512 * 2;
  unsigned short* Paug = (unsigned short*)p;  p += (size_t)192 * 1024 * 2;
  unsigned short* Xp   = (unsigned short*)p;  p += (size_t)2048 * 512 * 2;
  unsigned short* relb = (unsigned short*)p;  p += (size_t)2048 * 512 * 2;
  float* outp = (float*)d_out;

  prep_kernel<<<3137, 256, 0, stream>>>(x, rel, pos_e, pos_r, maskv, We_q,
                                        We_k, Wr_k, We_v, Wr_v, be_k, br_k,
                                        Xp, relb, Weqb, Wkb, WekT, Bt, Paug);
  g1_kernel<<<560, 256, 0, stream>>>(Xp, Weqb, be_q, relb, Wkb, Paug, Bt, qb,
                                     RW, GP);
  g2_kernel<<<384, 256, 0, stream>>>(qb, WekT, GP, qke, sd);
  attn_kernel<<<2048, 512, 0, stream>>>(x, rel, qke, sd, qb, RW, A, spe, spr);
  out_mfma_kernel<<<dim3(8, 32), 256, 0, stream>>>(A, Bt, be_v, br_v, spe, spr,
                                                   outp);
}

// Round 9
// 130.449 us; speedup vs baseline: 1.1923x; 1.1923x over previous
//
#include <hip/hip_runtime.h>
#include <math.h>

// B=2048, L=64, D=512. Only out[:,0] needed.
// q = (x0+pe0)@We_q^T + be_q (bf16). All score terms from q:
//   QKE[b,d] = sum_n q[b,n]*We_k[n,d]  (B = WekT = We_k^T, +rows be_k/br_k -> qbk/qbr)
//   SD[b,j]  = sum_n q[b,n]*GP[j,n],  GP = Paug@Wkb^T (weights-only)
//   RW[b,n]  = sum_d rel[b,d]*Wr_k[n,d];  crr = q.RW + qbr
// attn (one block per b): wave w stages rows 8w..8w+7 of x[b] to LDS (bf16)
//   AND dots them vs QKE in the same pass (fp32, 4-row chunked load issue);
//   softmax; vectorized wave-split weighted sum ->
//   A[b] = [sum p_j x_j | spr*rel | p(129) | 0].
// out = A@Bt^T + spe*be_v + spr*br_v;  Bt = [We_v|Wr_v | U^T | 0], U = Paug@Wvb^T.

using s16x8 = __attribute__((ext_vector_type(8))) short;
using f32x4 = __attribute__((ext_vector_type(4))) float;

#define S12 1216

static __device__ __forceinline__ float bf2f(unsigned short s) {
  union { unsigned u; float f; } c; c.u = ((unsigned)s) << 16; return c.f;
}
static __device__ __forceinline__ unsigned short f2bf(float f) {
  union { float f; unsigned u; } c; c.f = f;
  unsigned u = c.u;
  unsigned r = (u + 0x7fffu + ((u >> 16) & 1u)) >> 16;
  return (unsigned short)r;
}

template <int K>
__device__ __forceinline__ void mfma64(
    const unsigned short* __restrict__ Ab, int lda,
    const unsigned short* __restrict__ Bb, int ldb,
    int wm, int wn, int lr, int koff, f32x4 acc[2][2]) {
#pragma unroll
  for (int k0 = 0; k0 < K; k0 += 32) {
    s16x8 a[2], b[2];
#pragma unroll
    for (int im = 0; im < 2; ++im)
      a[im] = *(const s16x8*)(Ab + (size_t)(wm + im * 16 + lr) * lda + k0 + koff);
#pragma unroll
    for (int in = 0; in < 2; ++in)
      b[in] = *(const s16x8*)(Bb + (size_t)(wn + in * 16 + lr) * ldb + k0 + koff);
#pragma unroll
    for (int im = 0; im < 2; ++im)
#pragma unroll
      for (int in = 0; in < 2; ++in)
        acc[im][in] = __builtin_amdgcn_mfma_f32_16x16x32_bf16(a[im], b[in], acc[im][in], 0, 0, 0);
  }
}

// ---------------- prep ----------------
__global__ __launch_bounds__(256) void prep_kernel(
    const float* __restrict__ x, const float* __restrict__ rel,
    const float* __restrict__ pos_e, const float* __restrict__ pos_r,
    const float* __restrict__ maskv, const float* __restrict__ We_q,
    const float* __restrict__ We_k, const float* __restrict__ Wr_k,
    const float* __restrict__ We_v, const float* __restrict__ Wr_v,
    const float* __restrict__ be_k, const float* __restrict__ br_k,
    unsigned short* __restrict__ Xp, unsigned short* __restrict__ relb,
    unsigned short* __restrict__ Weqb, unsigned short* __restrict__ Wkb,
    unsigned short* __restrict__ WekT, unsigned short* __restrict__ Bt,
    unsigned short* __restrict__ Paug) {
  const int blk = blockIdx.x, tid = threadIdx.x;
  __shared__ float ts[64][65];
  if (blk < 2048) {
    float2 v = *(const float2*)(x + (size_t)blk * 32768 + tid * 2);
    float2 pe = *(const float2*)(pos_e + tid * 2);
    ushort2 o;
    o.x = f2bf(v.x + pe.x);
    o.y = f2bf(v.y + pe.y);
    *(ushort2*)(Xp + (size_t)blk * 512 + tid * 2) = o;
    float2 rv = *(const float2*)(rel + (size_t)blk * 512 + tid * 2);
    ushort2 ro;
    ro.x = f2bf(rv.x);
    ro.y = f2bf(rv.y);
    *(ushort2*)(relb + (size_t)blk * 512 + tid * 2) = ro;
  } else if (blk < 2176) {
    const int e = ((blk - 2048) * 256 + tid) * 8;
    float4 a0 = *(const float4*)(We_q + e);
    float4 a1 = *(const float4*)(We_q + e + 4);
    ushort4 o0, o1;
    o0.x = f2bf(a0.x); o0.y = f2bf(a0.y); o0.z = f2bf(a0.z); o0.w = f2bf(a0.w);
    o1.x = f2bf(a1.x); o1.y = f2bf(a1.y); o1.z = f2bf(a1.z); o1.w = f2bf(a1.w);
    *(ushort4*)(Weqb + e) = o0;
    *(ushort4*)(Weqb + e + 4) = o1;
  } else if (blk < 2432) {
    const int e = ((blk - 2176) * 256 + tid) * 8;
    const int n = e >> 10, k = e & 1023;
    const float* src = (k < 512) ? (We_k + (size_t)n * 512 + k)
                                 : (Wr_k + (size_t)n * 512 + k - 512);
    float4 v0 = *(const float4*)src;
    float4 v1 = *(const float4*)(src + 4);
    ushort4 o0, o1;
    o0.x = f2bf(v0.x); o0.y = f2bf(v0.y); o0.z = f2bf(v0.z); o0.w = f2bf(v0.w);
    o1.x = f2bf(v1.x); o1.y = f2bf(v1.y); o1.z = f2bf(v1.z); o1.w = f2bf(v1.w);
    *(ushort4*)(Wkb + e) = o0;
    *(ushort4*)(Wkb + e + 4) = o1;
  } else if (blk < 2496) {
    const int tr = blk - 2432;
    const int td0 = (tr >> 3) * 64, tn0 = (tr & 7) * 64;
    const int r = tid >> 2, cq = (tid & 3) * 16;
#pragma unroll
    for (int i = 0; i < 16; i += 4) {
      float4 v = *(const float4*)(We_k + (size_t)(tn0 + r) * 512 + td0 + cq + i);
      ts[r][cq + i + 0] = v.x;
      ts[r][cq + i + 1] = v.y;
      ts[r][cq + i + 2] = v.z;
      ts[r][cq + i + 3] = v.w;
    }
    __syncthreads();
#pragma unroll
    for (int i = 0; i < 16; i += 4) {
      ushort4 o;
      o.x = f2bf(ts[cq + i + 0][r]);
      o.y = f2bf(ts[cq + i + 1][r]);
      o.z = f2bf(ts[cq + i + 2][r]);
      o.w = f2bf(ts[cq + i + 3][r]);
      *(ushort4*)(WekT + (size_t)(td0 + r) * 512 + tn0 + cq + i) = o;
    }
  } else if (blk == 2496) {
    WekT[(size_t)512 * 512 + tid] = f2bf(be_k[tid]);
    WekT[(size_t)512 * 512 + 256 + tid] = f2bf(be_k[256 + tid]);
    WekT[(size_t)513 * 512 + tid] = f2bf(br_k[tid]);
    WekT[(size_t)513 * 512 + 256 + tid] = f2bf(br_k[256 + tid]);
  } else if (blk < 2513) {
    const int e = ((blk - 2497) * 256 + tid) * 8;
    if (e < 62 * 512) {
      ushort4 z = {0, 0, 0, 0};
      *(ushort4*)(WekT + (size_t)514 * 512 + e) = z;
      *(ushort4*)(WekT + (size_t)514 * 512 + e + 4) = z;
    }
  } else if (blk < 3025) {
    const int base = ((blk - 2513) * 256 + tid) * 4;
    const int n = base >> 10, k = base & 1023;
    const float* src = (k < 512) ? (We_v + (size_t)n * 512 + k)
                                 : (Wr_v + (size_t)n * 512 + k - 512);
    float4 v = *(const float4*)src;
    ushort4 o;
    o.x = f2bf(v.x); o.y = f2bf(v.y); o.z = f2bf(v.z); o.w = f2bf(v.w);
    *(ushort4*)(Bt + (size_t)n * S12 + k) = o;
  } else if (blk < 3041) {
    const int t = (blk - 3025) * 256 + tid;
    const int n = t >> 3, c0 = 1152 + (t & 7) * 8;
    ushort4 z = {0, 0, 0, 0};
    *(ushort4*)(Bt + (size_t)n * S12 + c0) = z;
    *(ushort4*)(Bt + (size_t)n * S12 + c0 + 4) = z;
  } else {
    const int idx = (blk - 3041) * 256 + tid;
    const int e = idx * 8;
    const int j = e >> 10, c = e & 1023;
    ushort4 o0 = {0, 0, 0, 0}, o1 = {0, 0, 0, 0};
    if (j < 65 && c < 512) {
      float4 v0 = *(const float4*)(pos_e + (size_t)j * 512 + c);
      float4 v1 = *(const float4*)(pos_e + (size_t)j * 512 + c + 4);
      if (j == 64) {
        float4 m0 = *(const float4*)(maskv + c);
        float4 m1 = *(const float4*)(maskv + c + 4);
        v0.x += m0.x; v0.y += m0.y; v0.z += m0.z; v0.w += m0.w;
        v1.x += m1.x; v1.y += m1.y; v1.z += m1.z; v1.w += m1.w;
      }
      o0.x = f2bf(v0.x); o0.y = f2bf(v0.y); o0.z = f2bf(v0.z); o0.w = f2bf(v0.w);
      o1.x = f2bf(v1.x); o1.y = f2bf(v1.y); o1.z = f2bf(v1.z); o1.w = f2bf(v1.w);
    } else if (j >= 65 && j < 129 && c >= 512) {
      float4 v0 = *(const float4*)(pos_r + (size_t)(j - 65) * 512 + c - 512);
      float4 v1 = *(const float4*)(pos_r + (size_t)(j - 65) * 512 + c - 512 + 4);
      o0.x = f2bf(v0.x); o0.y = f2bf(v0.y); o0.z = f2bf(v0.z); o0.w = f2bf(v0.w);
      o1.x = f2bf(v1.x); o1.y = f2bf(v1.y); o1.z = f2bf(v1.z); o1.w = f2bf(v1.w);
    }
    *(ushort4*)(Paug + e) = o0;
    *(ushort4*)(Paug + e + 4) = o1;
  }
}

// ---- g1: q | RW | GP | U ----
__global__ __launch_bounds__(256) void g1_kernel(
    const unsigned short* __restrict__ Xp, const unsigned short* __restrict__ Weqb,
    const float* __restrict__ be_q, const unsigned short* __restrict__ relb,
    const unsigned short* __restrict__ Wkb, const unsigned short* __restrict__ Paug,
    unsigned short* __restrict__ Bt, unsigned short* __restrict__ qb,
    float* __restrict__ RW, unsigned short* __restrict__ GP) {
  int blk = blockIdx.x;
  const int tid = threadIdx.x;
  const int wid = tid >> 6, lane = tid & 63;
  const int wm = (wid >> 1) * 32, wn = (wid & 1) * 32;
  const int lr = lane & 15, koff = (lane >> 4) * 8;
  const int r0 = (lane >> 4) * 4;
  f32x4 acc[2][2] = {};
  if (blk < 256) {
    const int bm = (blk >> 3) * 64, bn = (blk & 7) * 64;
    mfma64<512>(Xp + (size_t)bm * 512, 512, Weqb + (size_t)bn * 512, 512,
                wm, wn, lr, koff, acc);
#pragma unroll
    for (int im = 0; im < 2; ++im)
#pragma unroll
      for (int in = 0; in < 2; ++in)
#pragma unroll
        for (int i = 0; i < 4; ++i) {
          const int row = bm + wm + im * 16 + r0 + i;
          const int col = bn + wn + in * 16 + lr;
          qb[(size_t)row * 512 + col] = f2bf(acc[im][in][i] + be_q[col]);
        }
  } else if (blk < 512) {
    blk -= 256;
    const int bm = (blk >> 3) * 64, bn = (blk & 7) * 64;
    mfma64<512>(relb + (size_t)bm * 512, 512, Wkb + (size_t)bn * 1024 + 512, 1024,
                wm, wn, lr, koff, acc);
#pragma unroll
    for (int im = 0; im < 2; ++im)
#pragma unroll
      for (int in = 0; in < 2; ++in)
#pragma unroll
        for (int i = 0; i < 4; ++i) {
          const int row = bm + wm + im * 16 + r0 + i;
          const int col = bn + wn + in * 16 + lr;
          RW[(size_t)row * 512 + col] = acc[im][in][i];
        }
  } else if (blk < 536) {
    blk -= 512;
    const int bm = (blk >> 3) * 64, bn = (blk & 7) * 64;
    mfma64<1024>(Paug + (size_t)bm * 1024, 1024, Wkb + (size_t)bn * 1024, 1024,
                 wm, wn, lr, koff, acc);
#pragma unroll
    for (int im = 0; im < 2; ++im)
#pragma unroll
      for (int in = 0; in < 2; ++in)
#pragma unroll
        for (int i = 0; i < 4; ++i) {
          const int row = bm + wm + im * 16 + r0 + i;
          const int col = bn + wn + in * 16 + lr;
          GP[(size_t)row * 512 + col] = f2bf(acc[im][in][i]);
        }
  } else {
    blk -= 536;
    const int bm = (blk >> 3) * 64, bn = (blk & 7) * 64;
    mfma64<1024>(Paug + (size_t)bm * 1024, 1024, Bt + (size_t)bn * S12, S12,
                 wm, wn, lr, koff, acc);
#pragma unroll
    for (int im = 0; im < 2; ++im)
#pragma unroll
      for (int in = 0; in < 2; ++in)
#pragma unroll
        for (int i = 0; i < 4; ++i) {
          const int row = bm + wm + im * 16 + r0 + i;
          const int col = bn + wn + in * 16 + lr;
          if (row < 129)
            Bt[(size_t)col * S12 + 1024 + row] = f2bf(acc[im][in][i]);
        }
  }
}

// ---- g2: QKE (fp32, incl qbk/qbr) | SD (fp32) ----
__global__ __launch_bounds__(256) void g2_kernel(
    const unsigned short* __restrict__ qb, const unsigned short* __restrict__ WekT,
    const unsigned short* __restrict__ GP, float* __restrict__ qke,
    float* __restrict__ sd) {
  int blk = blockIdx.x;
  const int tid = threadIdx.x;
  const int wid = tid >> 6, lane = tid & 63;
  const int wm = (wid >> 1) * 32, wn = (wid & 1) * 32;
  const int lr = lane & 15, koff = (lane >> 4) * 8;
  const int r0 = (lane >> 4) * 4;
  f32x4 acc[2][2] = {};
  if (blk < 288) {
    const int bm = (blk / 9) * 64, bn = (blk % 9) * 64;
    mfma64<512>(qb + (size_t)bm * 512, 512, WekT + (size_t)bn * 512, 512,
                wm, wn, lr, koff, acc);
#pragma unroll
    for (int im = 0; im < 2; ++im)
#pragma unroll
      for (int in = 0; in < 2; ++in)
#pragma unroll
        for (int i = 0; i < 4; ++i) {
          const int row = bm + wm + im * 16 + r0 + i;
          const int col = bn + wn + in * 16 + lr;
          qke[(size_t)row * 576 + col] = acc[im][in][i];
        }
  } else {
    blk -= 288;
    const int bm = (blk / 3) * 64, bn = (blk % 3) * 64;
    mfma64<512>(qb + (size_t)bm * 512, 512, GP + (size_t)bn * 512, 512,
                wm, wn, lr, koff, acc);
#pragma unroll
    for (int im = 0; im < 2; ++im)
#pragma unroll
      for (int in = 0; in < 2; ++in)
#pragma unroll
        for (int i = 0; i < 4; ++i) {
          const int row = bm + wm + im * 16 + r0 + i;
          const int col = bn + wn + in * 16 + lr;
          sd[(size_t)row * 192 + col] = acc[im][in][i];
        }
  }
}

// ---------------- attn: fused stage+score (chunked loads), vec epilogue ----------------
__global__ __launch_bounds__(512, 4) void attn_kernel(
    const float* __restrict__ x, const float* __restrict__ rel,
    const float* __restrict__ qke, const float* __restrict__ sd,
    const unsigned short* __restrict__ qb, const float* __restrict__ RW,
    unsigned short* __restrict__ A, float* __restrict__ spe_g,
    float* __restrict__ spr_g) {
  __shared__ unsigned short xs[64 * 512];   // 64 KB bf16
  __shared__ unsigned short part[8 * 512];  // 8 KB bf16 partials
  __shared__ float sdl[192];
  __shared__ float sc[64];
  __shared__ float pvv[129];
  __shared__ float scx[8];
  const int b = blockIdx.x;
  const int tid = threadIdx.x;
  const int wid = tid >> 6, lane = tid & 63;
  const int j0 = wid * 8;
  const float scale = 0.04419417382415922f;  // 1/sqrt(512)
  const float* xb = x + (size_t)b * 32768;

  if (tid < 192) sdl[tid] = sd[(size_t)b * 192 + tid];
  if (tid == 200) scx[1] = qke[(size_t)b * 576 + 512];  // qbk
  float qe[8];
  {
    float4 a0 = *(const float4*)(qke + (size_t)b * 576 + lane * 8);
    float4 a1 = *(const float4*)(qke + (size_t)b * 576 + lane * 8 + 4);
    qe[0] = a0.x; qe[1] = a0.y; qe[2] = a0.z; qe[3] = a0.w;
    qe[4] = a1.x; qe[5] = a1.y; qe[6] = a1.z; qe[7] = a1.w;
  }

  // fused stage+score: wave w owns rows j0..j0+7; loads issued in 4-row chunks
  {
    float a8[8];
#pragma unroll
    for (int c = 0; c < 2; ++c) {
      float4 w0[4], w1[4];
#pragma unroll
      for (int r = 0; r < 4; ++r) {
        const int j = j0 + c * 4 + r;
        w0[r] = *(const float4*)(xb + (size_t)j * 512 + lane * 8);
        w1[r] = *(const float4*)(xb + (size_t)j * 512 + lane * 8 + 4);
      }
#pragma unroll
      for (int r = 0; r < 4; ++r) {
        const int j = j0 + c * 4 + r;
        s16x8 u;
        u[0] = (short)f2bf(w0[r].x); u[1] = (short)f2bf(w0[r].y);
        u[2] = (short)f2bf(w0[r].z); u[3] = (short)f2bf(w0[r].w);
        u[4] = (short)f2bf(w1[r].x); u[5] = (short)f2bf(w1[r].y);
        u[6] = (short)f2bf(w1[r].z); u[7] = (short)f2bf(w1[r].w);
        *(s16x8*)(xs + (size_t)j * 512 + lane * 8) = u;
        a8[c * 4 + r] =
            qe[0] * w0[r].x + qe[1] * w0[r].y + qe[2] * w0[r].z + qe[3] * w0[r].w +
            qe[4] * w1[r].x + qe[5] * w1[r].y + qe[6] * w1[r].z + qe[7] * w1[r].w;
      }
    }
#pragma unroll
    for (int off = 32; off > 0; off >>= 1) {
#pragma unroll
      for (int r = 0; r < 8; ++r) a8[r] += __shfl_xor(a8[r], off);
    }
    if (lane == 0) {
#pragma unroll
      for (int r = 0; r < 8; ++r) sc[j0 + r] = a8[r];
    }
  }
  if (wid == 7) {  // crr = q.RW + qbr
    s16x8 qv = *(const s16x8*)(qb + (size_t)b * 512 + lane * 8);
    float4 r0 = *(const float4*)(RW + (size_t)b * 512 + lane * 8);
    float4 r1 = *(const float4*)(RW + (size_t)b * 512 + lane * 8 + 4);
    float s = bf2f(qv[0]) * r0.x + bf2f(qv[1]) * r0.y + bf2f(qv[2]) * r0.z +
              bf2f(qv[3]) * r0.w + bf2f(qv[4]) * r1.x + bf2f(qv[5]) * r1.y +
              bf2f(qv[6]) * r1.z + bf2f(qv[7]) * r1.w;
#pragma unroll
    for (int off = 32; off > 0; off >>= 1) s += __shfl_xor(s, off);
    if (lane == 0) scx[0] = s + qke[(size_t)b * 576 + 513];
  }
  __syncthreads();

  // softmax over 129 (wave 0)
  if (wid == 0) {
    const float crr = scx[0];
    const float qbk = scx[1];
    float v1 = (sc[lane] + sdl[lane] + qbk) * scale;
    float v2 = (lane == 0) ? (sdl[64] + qbk) * scale : (sdl[64 + lane] + crr) * scale;
    float v3 = (lane == 0) ? (sdl[128] + crr) * scale : -1e30f;
    float m = fmaxf(fmaxf(v1, v2), v3);
#pragma unroll
    for (int off = 32; off > 0; off >>= 1) m = fmaxf(m, __shfl_xor(m, off));
    float e1 = __expf(v1 - m);
    float e2 = __expf(v2 - m);
    float e3 = (lane == 0) ? __expf(v3 - m) : 0.f;
    float se = e1 + ((lane == 0) ? e2 : 0.f);
    float sr = ((lane == 0) ? 0.f : e2) + e3;
#pragma unroll
    for (int off = 32; off > 0; off >>= 1) {
      se += __shfl_xor(se, off);
      sr += __shfl_xor(sr, off);
    }
    float inv = 1.f / (se + sr);
    float p1 = e1 * inv, p2 = e2 * inv;
    pvv[lane] = p1;
    pvv[64 + lane] = p2;
    unsigned short* Ab = A + (size_t)b * S12;
    Ab[1024 + lane] = f2bf(p1);
    Ab[1088 + lane] = f2bf(p2);
    if (lane == 0) {
      float p3 = e3 * inv;
      pvv[128] = p3;
      Ab[1152] = f2bf(p3);
      scx[4] = sr * inv;
      spe_g[b] = se * inv;
      spr_g[b] = sr * inv;
    } else {
      Ab[1152 + lane] = 0;
    }
  }
  __syncthreads();

  // epilogue: wave w sums its 8 rows (vector LDS reads) -> bf16 partials
  {
    float acc8[8] = {};
#pragma unroll
    for (int r = 0; r < 8; ++r) {
      const float p = pvv[j0 + r];
      s16x8 xv = *(const s16x8*)(xs + (size_t)(j0 + r) * 512 + lane * 8);
      acc8[0] += p * bf2f(xv[0]); acc8[1] += p * bf2f(xv[1]);
      acc8[2] += p * bf2f(xv[2]); acc8[3] += p * bf2f(xv[3]);
      acc8[4] += p * bf2f(xv[4]); acc8[5] += p * bf2f(xv[5]);
      acc8[6] += p * bf2f(xv[6]); acc8[7] += p * bf2f(xv[7]);
    }
    s16x8 o;
#pragma unroll
    for (int i = 0; i < 8; ++i) o[i] = (short)f2bf(acc8[i]);
    *(s16x8*)(part + wid * 512 + lane * 8) = o;
  }
  __syncthreads();
  {
    float s = 0.f;
#pragma unroll
    for (int w = 0; w < 8; ++w) s += bf2f(part[w * 512 + tid]);
    unsigned short* Ab = A + (size_t)b * S12;
    Ab[tid] = f2bf(s);
    Ab[512 + tid] = f2bf(scx[4] * rel[(size_t)b * 512 + tid]);
  }
}

// ---- out = A @ Bt^T + spe*be_v + spr*br_v ----
__global__ __launch_bounds__(256) void out_mfma_kernel(
    const unsigned short* __restrict__ A, const unsigned short* __restrict__ Bt,
    const float* __restrict__ be_v, const float* __restrict__ br_v,
    const float* __restrict__ spe, const float* __restrict__ spr,
    float* __restrict__ outp) {
  const int bn = blockIdx.x * 64;
  const int bm = blockIdx.y * 64;
  const int tid = threadIdx.x;
  const int wid = tid >> 6, lane = tid & 63;
  const int wm = (wid >> 1) * 32, wn = (wid & 1) * 32;
  const int lr = lane & 15, koff = (lane >> 4) * 8;
  f32x4 acc[2][2] = {};
  mfma64<S12>(A + (size_t)bm * S12, S12, Bt + (size_t)bn * S12, S12,
              wm, wn, lr, koff, acc);
  const int r0 = (lane >> 4) * 4;
#pragma unroll
  for (int im = 0; im < 2; ++im)
#pragma unroll
    for (int i = 0; i < 4; ++i) {
      const int row = bm + wm + im * 16 + r0 + i;
      const float se = spe[row], sr = spr[row];
#pragma unroll
      for (int in = 0; in < 2; ++in) {
        const int col = bn + wn + in * 16 + lr;
        outp[(size_t)row * 512 + col] = acc[im][in][i] + se * be_v[col] + sr * br_v[col];
      }
    }
}

extern "C" void kernel_launch(void* const* d_in, const int* in_sizes, int n_in,
                              void* d_out, int out_size, void* d_ws, size_t ws_size,
                              hipStream_t stream) {
  const float* x     = (const float*)d_in[0];
  const float* rel   = (const float*)d_in[1];
  const float* maskv = (const float*)d_in[2];
  const float* pos_e = (const float*)d_in[3];
  const float* pos_r = (const float*)d_in[4];
  const float* We_q  = (const float*)d_in[5];
  const float* be_q  = (const float*)d_in[6];
  const float* We_k  = (const float*)d_in[7];
  const float* be_k  = (const float*)d_in[8];
  const float* We_v  = (const float*)d_in[9];
  const float* be_v  = (const float*)d_in[10];
  const float* Wr_k  = (const float*)d_in[13];
  const float* br_k  = (const float*)d_in[14];
  const float* Wr_v  = (const float*)d_in[15];
  const float* br_v  = (const float*)d_in[16];

  char* p = (char*)d_ws;
  float* qke = (float*)p;                     p += (size_t)2048 * 576 * 4;
  float* sd  = (float*)p;                     p += (size_t)2048 * 192 * 4;
  float* RW  = (float*)p;                     p += (size_t)2048 * 512 * 4;
  float* spe = (float*)p;                     p += 2048 * 4;
  float* spr = (float*)p;                     p += 2048 * 4;
  unsigned short* qb   = (unsigned short*)p;  p += (size_t)2048 * 512 * 2;
  unsigned short* A    = (unsigned short*)p;  p += (size_t)2048 * S12 * 2;
  unsigned short* Bt   = (unsigned short*)p;  p += (size_t)512 * S12 * 2;
  unsigned short* WekT = (unsigned short*)p;  p += (size_t)576 * 512 * 2;
  unsigned short* Weqb = (unsigned short*)p;  p += (size_t)512 * 512 * 2;
  unsigned short* Wkb  = (unsigned short*)p;  p += (size_t)512 * 1024 * 2;
  unsigned short* GP   = (unsigned short*)p;  p += (size_t)192 * 512 * 2;
  unsigned short* Paug = (unsigned short*)p;  p += (size_t)192 * 1024 * 2;
  unsigned short* Xp   = (unsigned short*)p;  p += (size_t)2048 * 512 * 2;
  unsigned short* relb = (unsigned short*)p;  p += (size_t)2048 * 512 * 2;
  float* outp = (float*)d_out;

  prep_kernel<<<3137, 256, 0, stream>>>(x, rel, pos_e, pos_r, maskv, We_q,
                                        We_k, Wr_k, We_v, Wr_v, be_k, br_k,
                                        Xp, relb, Weqb, Wkb, WekT, Bt, Paug);
  g1_kernel<<<560, 256, 0, stream>>>(Xp, Weqb, be_q, relb, Wkb, Paug, Bt, qb,
                                     RW, GP);
  g2_kernel<<<384, 256, 0, stream>>>(qb, WekT, GP, qke, sd);
  attn_kernel<<<2048, 512, 0, stream>>>(x, rel, qke, sd, qb, RW, A, spe, spr);
  out_mfma_kernel<<<dim3(8, 32), 256, 0, stream>>>(A, Bt, be_v, br_v, spe, spr,
                                                   outp);
}